// Round 1
// baseline (193.061 us; speedup 1.0000x reference)
//
#include <hip/hip_runtime.h>

#define EMBED 32
#define LSEQ  512
#define LCH   128
#define NCH   (LSEQ / LCH)

// One block = 256 threads = 256 query rows of one batch half.
// Each thread: rgn row in regs, online-softmax flash attention over wrd
// (staged in LDS in 128-row chunks, broadcast reads), then the 3x(32x32) MLP.
__global__ __launch_bounds__(256, 4)
void refine_fused(const float* __restrict__ rgn,
                  const float* __restrict__ wrd,
                  const float* __restrict__ Wsc,
                  const float* __restrict__ bsc,
                  const float* __restrict__ W1,
                  const float* __restrict__ b1,
                  const float* __restrict__ W2,
                  const float* __restrict__ b2,
                  float* __restrict__ out)
{
    __shared__ float wch[LCH * EMBED];       // 16 KB wrd chunk
    __shared__ float sW[3][EMBED * EMBED];   // 12 KB weights
    __shared__ float sb[3][EMBED];           // biases

    const int tid = threadIdx.x;
    const int bid = blockIdx.x;
    const int b   = bid >> 1;
    const int q   = ((bid & 1) << 8) | tid;  // 0..511

    // --- stage MLP weights (once per block) ---
    {
        float4*       dW = (float4*)&sW[0][0];
        const float4* s0 = (const float4*)Wsc;
        const float4* s1 = (const float4*)W1;
        const float4* s2 = (const float4*)W2;
        dW[tid]       = s0[tid];   // 256 float4 = 1024 floats each
        dW[256 + tid] = s1[tid];
        dW[512 + tid] = s2[tid];
        if (tid < 8)       ((float4*)&sb[0][0])[tid]      = ((const float4*)bsc)[tid];
        else if (tid < 16) ((float4*)&sb[1][0])[tid - 8]  = ((const float4*)b1)[tid - 8];
        else if (tid < 24) ((float4*)&sb[2][0])[tid - 16] = ((const float4*)b2)[tid - 16];
    }

    // --- this thread's rgn row into registers ---
    float a[EMBED];
    {
        const float4* rv = (const float4*)(rgn + ((size_t)b * LSEQ + q) * EMBED);
        #pragma unroll
        for (int i = 0; i < EMBED / 4; ++i) {
            float4 t = rv[i];
            a[4*i+0] = t.x; a[4*i+1] = t.y; a[4*i+2] = t.z; a[4*i+3] = t.w;
        }
    }

    float m = -1e30f;   // deferred-rescale softmax base
    float l = 0.f;
    float O[EMBED];
    #pragma unroll
    for (int d = 0; d < EMBED; ++d) O[d] = 0.f;

    for (int c = 0; c < NCH; ++c) {
        __syncthreads();
        {   // cooperative chunk load: 1024 float4, 4 per thread, coalesced
            const float4* src = (const float4*)(wrd + ((size_t)b * LSEQ + c * LCH) * EMBED);
            float4* dst = (float4*)wch;
            #pragma unroll
            for (int i = 0; i < (LCH * EMBED / 4) / 256; ++i)
                dst[i * 256 + tid] = src[i * 256 + tid];
        }
        __syncthreads();

        for (int s = 0; s < LCH; ++s) {
            // load wrd[s][:] once (broadcast across lanes), reuse for dot + accum
            const float4* w4 = (const float4*)&wch[s * EMBED];
            float4 t0 = w4[0], t1 = w4[1], t2 = w4[2], t3 = w4[3];
            float4 t4 = w4[4], t5 = w4[5], t6 = w4[6], t7 = w4[7];
            float wv[EMBED] = {
                t0.x,t0.y,t0.z,t0.w, t1.x,t1.y,t1.z,t1.w,
                t2.x,t2.y,t2.z,t2.w, t3.x,t3.y,t3.z,t3.w,
                t4.x,t4.y,t4.z,t4.w, t5.x,t5.y,t5.z,t5.w,
                t6.x,t6.y,t6.z,t6.w, t7.x,t7.y,t7.z,t7.w };

            float c0 = 0.f, c1 = 0.f, c2 = 0.f, c3 = 0.f;
            #pragma unroll
            for (int d = 0; d < EMBED; d += 4) {
                c0 = fmaf(a[d+0], wv[d+0], c0);
                c1 = fmaf(a[d+1], wv[d+1], c1);
                c2 = fmaf(a[d+2], wv[d+2], c2);
                c3 = fmaf(a[d+3], wv[d+3], c3);
            }
            float dot = (c0 + c1) + (c2 + c3);
            float z = 4.f * (dot >= 0.f ? dot : 0.1f * dot);

            // deferred rescale: only when some lane would exceed exp range
            if (__any(z - m > 60.f)) {
                float mn = fmaxf(m, z);
                float r  = __expf(m - mn);   // exp(-inf)=0 on first trigger
                l *= r;
                #pragma unroll
                for (int d = 0; d < EMBED; ++d) O[d] *= r;
                m = mn;
            }
            float p = __expf(z - m);
            l += p;
            #pragma unroll
            for (int d = 0; d < EMBED; ++d) O[d] = fmaf(p, wv[d], O[d]);
        }
    }

    // --- normalize ---
    float inv = 1.f / l;
    #pragma unroll
    for (int d = 0; d < EMBED; ++d) O[d] *= inv;

    // --- q = mean(wrd row) ---
    float qm = 0.f;
    {
        const float4* wv4 = (const float4*)(wrd + ((size_t)b * LSEQ + q) * EMBED);
        #pragma unroll
        for (int i = 0; i < 8; ++i) {
            float4 t = wv4[i];
            qm += (t.x + t.y) + (t.z + t.w);
        }
        qm *= (1.f / EMBED);
    }

    // --- scaling = tanh(O @ Wsc^T + bsc) ---
    float scl[EMBED];
    #pragma unroll
    for (int j = 0; j < EMBED; ++j) {
        float acc = sb[0][j];
        const float* wr = &sW[0][j * EMBED];
        #pragma unroll
        for (int d = 0; d < EMBED; ++d) acc = fmaf(O[d], wr[d], acc);
        float e = __expf(2.f * acc);         // tanh(x) = 1 - 2/(e^{2x}+1)
        scl[j] = 1.f - 2.f / (e + 1.f);
    }

    // --- h = relu(qm * (scl @ W1^T) + b1) ---
    float h[EMBED];
    #pragma unroll
    for (int j = 0; j < EMBED; ++j) {
        float acc = 0.f;
        const float* wr = &sW[1][j * EMBED];
        #pragma unroll
        for (int d = 0; d < EMBED; ++d) acc = fmaf(scl[d], wr[d], acc);
        acc = fmaf(qm, acc, sb[1][j]);
        h[j] = fmaxf(acc, 0.f);
    }

    // --- out = h @ W2^T + b2 + qm ---
    float res[EMBED];
    #pragma unroll
    for (int j = 0; j < EMBED; ++j) {
        float acc = sb[2][j];
        const float* wr = &sW[2][j * EMBED];
        #pragma unroll
        for (int d = 0; d < EMBED; ++d) acc = fmaf(h[d], wr[d], acc);
        res[j] = acc + qm;
    }
    float4* o4 = (float4*)(out + ((size_t)b * LSEQ + q) * EMBED);
    #pragma unroll
    for (int i = 0; i < 8; ++i)
        o4[i] = make_float4(res[4*i+0], res[4*i+1], res[4*i+2], res[4*i+3]);
}

extern "C" void kernel_launch(void* const* d_in, const int* in_sizes, int n_in,
                              void* d_out, int out_size, void* d_ws, size_t ws_size,
                              hipStream_t stream) {
    const float* rgn = (const float*)d_in[0];
    const float* wrd = (const float*)d_in[1];
    const float* Wsc = (const float*)d_in[2];
    const float* bsc = (const float*)d_in[3];
    const float* W1  = (const float*)d_in[4];
    const float* b1  = (const float*)d_in[5];
    const float* W2  = (const float*)d_in[6];
    const float* b2  = (const float*)d_in[7];
    float* out = (float*)d_out;

    dim3 grid(512);   // 256 batches x 2 query-halves
    dim3 block(256);
    hipLaunchKernelGGL(refine_fused, grid, block, 0, stream,
                       rgn, wrd, Wsc, bsc, W1, b1, W2, b2, out);
}

// Round 3
// 35.368 us; speedup vs baseline: 5.4586x; 5.4586x over previous
//
#include <hip/hip_runtime.h>

#define L_ 512

typedef _Float16 v8h __attribute__((ext_vector_type(8)));
typedef float    v4f __attribute__((ext_vector_type(4)));

#define MFMA(a,b,c) __builtin_amdgcn_mfma_f32_16x16x32_f16(a,b,c,0,0,0)

// One block per batch: 512 threads = 8 waves, wave w owns queries [w*64, w*64+64).
// LDS: wrd pre-fragmented for MFMA lane-linear reads (zero bank conflicts):
//   wfrag [s-tile][lane][8]  : QK^T A-operand, map (g,j) -> d = 8g+j
//   wtfrag[s-pair][dt][lane][8]: PV A-operand (wrd^T), map (g,j) -> s = 32p+16*(j>>2)+4g+(j&3)
// Every MFMA pairs A and B with the SAME slot->k map, so results are invariant
// to the hardware's internal k ordering; only the (m89-verified) C/D layout
// (col = lane&15, row = 4*(lane>>4)+i) is relied on, and it chains layer->layer.
__global__ __launch_bounds__(512, 2)
void attn_refine(const float* __restrict__ rgn, const float* __restrict__ wrd,
                 const float* __restrict__ Wsc, const float* __restrict__ bsc,
                 const float* __restrict__ W1,  const float* __restrict__ b1,
                 const float* __restrict__ W2,  const float* __restrict__ b2,
                 float* __restrict__ out)
{
    __shared__ __align__(16) _Float16 wfrag[32][64][8];       // 32 KB
    __shared__ __align__(16) _Float16 wtfrag[16][2][64][8];   // 32 KB

    const int tid  = threadIdx.x;
    const int lane = tid & 63;
    const int wv   = tid >> 6;     // wave 0..7
    const int bb   = blockIdx.x;   // batch
    const int g    = lane >> 4;    // k-group 0..3
    const int lc   = lane & 15;    // col lane (q)

    // ---- staging: thread owns wrd row s = tid ----
    {
        const v4f* wr4 = (const v4f*)(wrd + ((size_t)bb * L_ + tid) * 32);
        _Float16 wh[32];
        #pragma unroll
        for (int i = 0; i < 8; ++i) {
            v4f t = wr4[i];
            #pragma unroll
            for (int j = 0; j < 4; ++j) wh[4*i+j] = (_Float16)t[j];
        }
        const int st = tid >> 4, sr = tid & 15;
        #pragma unroll
        for (int c = 0; c < 4; ++c) {
            v8h pk;
            #pragma unroll
            for (int j = 0; j < 8; ++j) pk[j] = wh[8*c + j];
            *(v8h*)(&wfrag[st][sr + 16*c][0]) = pk;
        }
        const int pr   = tid >> 5;
        const int lgrp = 16 * ((tid >> 2) & 3);
        const int slot = (tid & 3) + 4 * ((tid >> 4) & 1);
        #pragma unroll
        for (int d = 0; d < 32; ++d)
            wtfrag[pr][d >> 4][(d & 15) + lgrp][slot] = wh[d];
    }

    // ---- rgn B-fragments (registers), map (g,j) -> d = 8g+j ----
    v8h qfrag[4];
    #pragma unroll
    for (int qt = 0; qt < 4; ++qt) {
        const v4f* rr = (const v4f*)(rgn + (((size_t)bb * L_) + wv*64 + qt*16 + lc) * 32 + g*8);
        v4f t0 = rr[0], t1 = rr[1];
        v8h f;
        #pragma unroll
        for (int j = 0; j < 4; ++j) { f[j] = (_Float16)t0[j]; f[4+j] = (_Float16)t1[j]; }
        qfrag[qt] = f;
    }

    __syncthreads();

    const v4f vzero = {0.f, 0.f, 0.f, 0.f};
    const float C1 = 5.770780163555851f;    // 4*log2(e)
    const float C2 = 0.5770780163555851f;   // 0.4*log2(e)  (leaky slope folded)

    // ---- pass 1: per-lane raw-dot max (leaky*lambda is monotone) ----
    float mraw[4] = {-3.0e38f, -3.0e38f, -3.0e38f, -3.0e38f};
    #pragma unroll 4
    for (int st = 0; st < 32; ++st) {
        v8h af = *(const v8h*)(&wfrag[st][lane][0]);
        #pragma unroll
        for (int qt = 0; qt < 4; ++qt) {
            v4f s = MFMA(af, qfrag[qt], vzero);
            mraw[qt] = fmaxf(mraw[qt], fmaxf(fmaxf(s[0], s[1]), fmaxf(s[2], s[3])));
        }
    }
    float nm[4];  // -z2max per q-tile (uniform across the 4 lanes sharing q)
    #pragma unroll
    for (int qt = 0; qt < 4; ++qt) {
        float v = mraw[qt];
        v = fmaxf(v, __shfl_xor(v, 16));
        v = fmaxf(v, __shfl_xor(v, 32));
        nm[qt] = -fmaxf(C1 * v, C2 * v);
    }

    // ---- pass 2: exp2 + PV (accumulate O^T in fp32 via MFMA) ----
    v4f  acc[4][2];
    float lsum[4];
    #pragma unroll
    for (int qt = 0; qt < 4; ++qt) { acc[qt][0] = vzero; acc[qt][1] = vzero; lsum[qt] = 0.f; }

    #pragma unroll 2
    for (int p = 0; p < 16; ++p) {
        v8h afa = *(const v8h*)(&wfrag[2*p  ][lane][0]);
        v8h afb = *(const v8h*)(&wfrag[2*p+1][lane][0]);
        v8h wt0 = *(const v8h*)(&wtfrag[p][0][lane][0]);
        v8h wt1 = *(const v8h*)(&wtfrag[p][1][lane][0]);
        #pragma unroll
        for (int qt = 0; qt < 4; ++qt) {
            v4f sa = MFMA(afa, qfrag[qt], vzero);
            v4f sb = MFMA(afb, qfrag[qt], vzero);
            v8h pb;
            #pragma unroll
            for (int i = 0; i < 4; ++i) {
                float pa = __builtin_amdgcn_exp2f(fmaxf(fmaf(C1, sa[i], nm[qt]), fmaf(C2, sa[i], nm[qt])));
                float pc = __builtin_amdgcn_exp2f(fmaxf(fmaf(C1, sb[i], nm[qt]), fmaf(C2, sb[i], nm[qt])));
                lsum[qt] += pa + pc;
                pb[i]   = (_Float16)pa;
                pb[4+i] = (_Float16)pc;
            }
            acc[qt][0] = MFMA(wt0, pb, acc[qt][0]);
            acc[qt][1] = MFMA(wt1, pb, acc[qt][1]);
        }
    }

    // ---- softmax denominator + qm (row mean of wrd, from f16 frags) ----
    float inv[4], qm[4];
    #pragma unroll
    for (int qt = 0; qt < 4; ++qt) {
        float l = lsum[qt];
        l += __shfl_xor(l, 16);
        l += __shfl_xor(l, 32);
        inv[qt] = 1.0f / l;
        float ssum = 0.f;
        #pragma unroll
        for (int c = 0; c < 4; ++c) {
            v8h r = *(const v8h*)(&wfrag[wv*4 + qt][lc + 16*c][0]);
            #pragma unroll
            for (int j = 0; j < 8; ++j) ssum += (float)r[j];
        }
        qm[qt] = ssum * 0.03125f;
    }

    // ---- MLP weight/bias fragments (registers) ----
    const float* Wp[3] = {Wsc, W1, W2};
    const float* bp[3] = {bsc, b1, b2};
    v8h Wf[3][2];
    v4f bv[3][2];
    #pragma unroll
    for (int ly = 0; ly < 3; ++ly) {
        #pragma unroll
        for (int jt = 0; jt < 2; ++jt) {
            const v4f ta = *(const v4f*)(Wp[ly] + (jt*16 + lc)*32 + g*4);
            const v4f tb = *(const v4f*)(Wp[ly] + (jt*16 + lc)*32 + 16 + g*4);
            v8h f;
            #pragma unroll
            for (int j = 0; j < 4; ++j) { f[j] = (_Float16)ta[j]; f[4+j] = (_Float16)tb[j]; }
            Wf[ly][jt] = f;
            bv[ly][jt] = *(const v4f*)(bp[ly] + jt*16 + g*4);
        }
    }

    // ---- MLP (all matmuls as MFMA, transposed form: y^T = W * x^T) ----
    const float CT = 2.885390081777927f;   // 2*log2(e)
    #pragma unroll
    for (int qt = 0; qt < 4; ++qt) {
        v8h xb;
        #pragma unroll
        for (int i = 0; i < 4; ++i) {
            xb[i]   = (_Float16)(acc[qt][0][i] * inv[qt]);
            xb[4+i] = (_Float16)(acc[qt][1][i] * inv[qt]);
        }
        v4f y0 = MFMA(Wf[0][0], xb, vzero);
        v4f y1 = MFMA(Wf[0][1], xb, vzero);
        v8h sb;
        #pragma unroll
        for (int i = 0; i < 4; ++i) {
            float t0 = y0[i] + bv[0][0][i];
            float t1 = y1[i] + bv[0][1][i];
            float e0 = __builtin_amdgcn_exp2f(CT * t0);
            float e1 = __builtin_amdgcn_exp2f(CT * t1);
            sb[i]   = (_Float16)(1.f - 2.f / (e0 + 1.f));   // tanh
            sb[4+i] = (_Float16)(1.f - 2.f / (e1 + 1.f));
        }
        v4f z0 = MFMA(Wf[1][0], sb, vzero);
        v4f z1 = MFMA(Wf[1][1], sb, vzero);
        v8h hb;
        #pragma unroll
        for (int i = 0; i < 4; ++i) {
            hb[i]   = (_Float16)fmaxf(fmaf(qm[qt], z0[i], bv[1][0][i]), 0.f);
            hb[4+i] = (_Float16)fmaxf(fmaf(qm[qt], z1[i], bv[1][1][i]), 0.f);
        }
        v4f r0 = MFMA(Wf[2][0], hb, vzero);
        v4f r1 = MFMA(Wf[2][1], hb, vzero);
        v4f o0, o1;
        #pragma unroll
        for (int i = 0; i < 4; ++i) {
            o0[i] = r0[i] + bv[2][0][i] + qm[qt];
            o1[i] = r1[i] + bv[2][1][i] + qm[qt];
        }
        float* ob = out + ((size_t)bb * L_ + wv*64 + qt*16 + lc) * 32;
        *(v4f*)(ob + g*4)      = o0;
        *(v4f*)(ob + 16 + g*4) = o1;
    }
}

extern "C" void kernel_launch(void* const* d_in, const int* in_sizes, int n_in,
                              void* d_out, int out_size, void* d_ws, size_t ws_size,
                              hipStream_t stream) {
    const float* rgn = (const float*)d_in[0];
    const float* wrd = (const float*)d_in[1];
    const float* Wsc = (const float*)d_in[2];
    const float* bsc = (const float*)d_in[3];
    const float* W1  = (const float*)d_in[4];
    const float* b1  = (const float*)d_in[5];
    const float* W2  = (const float*)d_in[6];
    const float* b2  = (const float*)d_in[7];
    float* out = (float*)d_out;

    attn_refine<<<dim3(256), dim3(512), 0, stream>>>(rgn, wrd, Wsc, bsc, W1, b1, W2, b2, out);
}